// Round 1
// baseline (1378.056 us; speedup 1.0000x reference)
//
#include <hip/hip_runtime.h>
#include <math.h>

#define BATCH 2
#define SEQ   2048
#define HID   1024
#define NH    16
#define HD    64
#define MROWS (BATCH * SEQ)   // 4096

// ---------------------------------------------------------------------------
// LayerNorm: one block per row, 256 threads, float4 per thread.
// ---------------------------------------------------------------------------
__global__ __launch_bounds__(256) void ln_kernel(const float* __restrict__ x,
                                                 const float* __restrict__ gamma,
                                                 const float* __restrict__ beta,
                                                 float* __restrict__ h)
{
    const int row = blockIdx.x;
    const int t = threadIdx.x;
    const float4 xv = ((const float4*)(x + (size_t)row * HID))[t];
    float s  = xv.x + xv.y + xv.z + xv.w;
    float ss = xv.x * xv.x + xv.y * xv.y + xv.z * xv.z + xv.w * xv.w;
#pragma unroll
    for (int off = 32; off > 0; off >>= 1) {
        s  += __shfl_down(s, off);
        ss += __shfl_down(ss, off);
    }
    __shared__ float red[8];
    const int wid = t >> 6;
    if ((t & 63) == 0) { red[wid] = s; red[4 + wid] = ss; }
    __syncthreads();
    s  = red[0] + red[1] + red[2] + red[3];
    ss = red[4] + red[5] + red[6] + red[7];
    const float mu   = s * (1.0f / HID);
    const float var  = ss * (1.0f / HID) - mu * mu;
    const float rstd = rsqrtf(var + 1e-12f);
    const float4 g  = ((const float4*)gamma)[t];
    const float4 bb = ((const float4*)beta)[t];
    float4 o;
    o.x = (xv.x - mu) * rstd * g.x + bb.x;
    o.y = (xv.y - mu) * rstd * g.y + bb.y;
    o.z = (xv.z - mu) * rstd * g.z + bb.z;
    o.w = (xv.w - mu) * rstd * g.w + bb.w;
    ((float4*)(h + (size_t)row * HID))[t] = o;
}

// ---------------------------------------------------------------------------
// GEMM: C[M,N] = A[M,K] * W[N,K]^T + bias[N].  A, W row-major (K contiguous).
// 128x128 tile, BK=16, 256 threads, 8x8 per thread, K-transposed LDS tiles.
// head_out: write C in [B, NH, S, HD] layout instead of [M, N].
// ---------------------------------------------------------------------------
#define BM 128
#define BN 128
#define BK 16
#define LDT 132   // padded row length of transposed tile [BK][LDT]

__global__ __launch_bounds__(256) void gemm_bias(const float* __restrict__ A,
                                                 const float* __restrict__ W,
                                                 const float* __restrict__ bias,
                                                 float* __restrict__ C,
                                                 int M, int N, int K, int head_out)
{
    __shared__ float As[BK][LDT];
    __shared__ float Ws[BK][LDT];
    const int t  = threadIdx.x;
    const int tx = t & 15;
    const int ty = t >> 4;
    const int bm = blockIdx.y * BM;
    const int bn = blockIdx.x * BN;

    float acc[8][8];
#pragma unroll
    for (int i = 0; i < 8; i++)
#pragma unroll
        for (int j = 0; j < 8; j++) acc[i][j] = 0.0f;

    const int lrow = t >> 1;        // 0..127
    const int lk   = (t & 1) * 8;   // 0 or 8
    const float* Ap = A + (size_t)(bm + lrow) * K + lk;
    const float* Wp = W + (size_t)(bn + lrow) * K + lk;

    for (int k0 = 0; k0 < K; k0 += BK) {
        const float4 a0 = *(const float4*)(Ap + k0);
        const float4 a1 = *(const float4*)(Ap + k0 + 4);
        const float4 w0 = *(const float4*)(Wp + k0);
        const float4 w1 = *(const float4*)(Wp + k0 + 4);
        __syncthreads();
        As[lk + 0][lrow] = a0.x; As[lk + 1][lrow] = a0.y;
        As[lk + 2][lrow] = a0.z; As[lk + 3][lrow] = a0.w;
        As[lk + 4][lrow] = a1.x; As[lk + 5][lrow] = a1.y;
        As[lk + 6][lrow] = a1.z; As[lk + 7][lrow] = a1.w;
        Ws[lk + 0][lrow] = w0.x; Ws[lk + 1][lrow] = w0.y;
        Ws[lk + 2][lrow] = w0.z; Ws[lk + 3][lrow] = w0.w;
        Ws[lk + 4][lrow] = w1.x; Ws[lk + 5][lrow] = w1.y;
        Ws[lk + 6][lrow] = w1.z; Ws[lk + 7][lrow] = w1.w;
        __syncthreads();
#pragma unroll
        for (int kk = 0; kk < BK; kk++) {
            float a[8], w[8];
            *(float4*)&a[0] = *(const float4*)&As[kk][ty * 8];
            *(float4*)&a[4] = *(const float4*)&As[kk][ty * 8 + 4];
            *(float4*)&w[0] = *(const float4*)&Ws[kk][tx * 8];
            *(float4*)&w[4] = *(const float4*)&Ws[kk][tx * 8 + 4];
#pragma unroll
            for (int i = 0; i < 8; i++)
#pragma unroll
                for (int j = 0; j < 8; j++) acc[i][j] += a[i] * w[j];
        }
    }

    float bvals[8];
#pragma unroll
    for (int j = 0; j < 8; j++) bvals[j] = bias[bn + tx * 8 + j];

    if (head_out) {
        const int n0 = bn + tx * 8;
        const int hh = n0 >> 6;     // head
        const int d0 = n0 & 63;     // dim within head (multiple of 8)
#pragma unroll
        for (int i = 0; i < 8; i++) {
            const int m  = bm + ty * 8 + i;
            const int bI = m >> 11;       // / SEQ
            const int sI = m & (SEQ - 1);
            float* dst = C + ((size_t)(bI * NH + hh) * SEQ + sI) * HD + d0;
            float4 o0, o1;
            o0.x = acc[i][0] + bvals[0]; o0.y = acc[i][1] + bvals[1];
            o0.z = acc[i][2] + bvals[2]; o0.w = acc[i][3] + bvals[3];
            o1.x = acc[i][4] + bvals[4]; o1.y = acc[i][5] + bvals[5];
            o1.z = acc[i][6] + bvals[6]; o1.w = acc[i][7] + bvals[7];
            *(float4*)dst       = o0;
            *(float4*)(dst + 4) = o1;
        }
    } else {
#pragma unroll
        for (int i = 0; i < 8; i++) {
            const int m = bm + ty * 8 + i;
            float* dst = C + (size_t)m * N + bn + tx * 8;
            float4 o0, o1;
            o0.x = acc[i][0] + bvals[0]; o0.y = acc[i][1] + bvals[1];
            o0.z = acc[i][2] + bvals[2]; o0.w = acc[i][3] + bvals[3];
            o1.x = acc[i][4] + bvals[4]; o1.y = acc[i][5] + bvals[5];
            o1.z = acc[i][6] + bvals[6]; o1.w = acc[i][7] + bvals[7];
            *(float4*)dst       = o0;
            *(float4*)(dst + 4) = o1;
        }
    }
}

// ---------------------------------------------------------------------------
// Flash attention (fp32): block = (q-tile of 64 rows, head, batch).
// 256 threads: thread = (r = t>>2 in 0..63, dp = t&3).
// KV tile = 32.  Online softmax, P through LDS, ctx written [B,S,HID].
// ---------------------------------------------------------------------------
#define KT 32

__global__ __launch_bounds__(256) void attn_kernel(const float* __restrict__ qg,
                                                   const float* __restrict__ kg,
                                                   const float* __restrict__ vg,
                                                   const float* __restrict__ maskg,
                                                   float* __restrict__ ctx)
{
    __shared__ float Qs[64][68];    // [r][d]
    __shared__ float Kst[HD][36];   // [d][c]  (transposed K tile)
    __shared__ float Vs[KT][68];    // [c][d]
    __shared__ float Ps[64][36];    // [r][c]
    __shared__ float Ms[KT];        // additive mask per kv col

    const int b  = blockIdx.z;
    const int hh = blockIdx.y;
    const int q0 = blockIdx.x * 64;
    const size_t headoff = ((size_t)(b * NH + hh)) * SEQ * HD;
    const float* Q = qg + headoff;
    const float* K = kg + headoff;
    const float* V = vg + headoff;

    const int t  = threadIdx.x;
    const int r  = t >> 2;   // q row 0..63
    const int dp = t & 3;    // chunk id

    // stage Q tile once
    {
        const float* src = Q + (size_t)(q0 + r) * HD + dp * 16;
#pragma unroll
        for (int j = 0; j < 16; j += 4)
            *(float4*)&Qs[r][dp * 16 + j] = *(const float4*)(src + j);
    }

    float O[16];
#pragma unroll
    for (int i = 0; i < 16; i++) O[i] = 0.0f;
    float mrun = -INFINITY, lrun = 0.0f;

    const int c2 = t >> 3;          // staging row 0..31
    const int d0 = (t & 7) * 8;     // staging d-chunk

    for (int c0 = 0; c0 < SEQ; c0 += KT) {
        __syncthreads();   // previous iteration's LDS reads complete
        // stage K (transposed) and V (natural)
        {
            const float* ksrc = K + (size_t)(c0 + c2) * HD + d0;
            const float4 f0 = *(const float4*)(ksrc);
            const float4 f1 = *(const float4*)(ksrc + 4);
            Kst[d0 + 0][c2] = f0.x; Kst[d0 + 1][c2] = f0.y;
            Kst[d0 + 2][c2] = f0.z; Kst[d0 + 3][c2] = f0.w;
            Kst[d0 + 4][c2] = f1.x; Kst[d0 + 5][c2] = f1.y;
            Kst[d0 + 6][c2] = f1.z; Kst[d0 + 7][c2] = f1.w;
            const float* vsrc = V + (size_t)(c0 + c2) * HD + d0;
            *(float4*)&Vs[c2][d0]     = *(const float4*)(vsrc);
            *(float4*)&Vs[c2][d0 + 4] = *(const float4*)(vsrc + 4);
            if (t < KT) Ms[t] = -1000.0f * (1.0f - maskg[b * SEQ + c0 + t]);
        }
        __syncthreads();

        // scores for c = dp*8 .. dp*8+7
        float sc[8];
#pragma unroll
        for (int i = 0; i < 8; i++) sc[i] = 0.0f;
#pragma unroll 4
        for (int kk4 = 0; kk4 < HD; kk4 += 4) {
            float qv[4];
            *(float4*)&qv[0] = *(const float4*)&Qs[r][kk4];
#pragma unroll
            for (int u = 0; u < 4; u++) {
                float kv[8];
                *(float4*)&kv[0] = *(const float4*)&Kst[kk4 + u][dp * 8];
                *(float4*)&kv[4] = *(const float4*)&Kst[kk4 + u][dp * 8 + 4];
#pragma unroll
                for (int i = 0; i < 8; i++) sc[i] += qv[u] * kv[i];
            }
        }
        float mx = -INFINITY;
#pragma unroll
        for (int i = 0; i < 8; i++) {
            sc[i] = sc[i] * 0.125f + Ms[dp * 8 + i];
            mx = fmaxf(mx, sc[i]);
        }
        mx = fmaxf(mx, __shfl_xor(mx, 1));
        mx = fmaxf(mx, __shfl_xor(mx, 2));
        const float mnew  = fmaxf(mrun, mx);
        const float alpha = __expf(mrun - mnew);
        float p[8];
        float psum = 0.0f;
#pragma unroll
        for (int i = 0; i < 8; i++) { p[i] = __expf(sc[i] - mnew); psum += p[i]; }
        psum += __shfl_xor(psum, 1);
        psum += __shfl_xor(psum, 2);
        lrun = lrun * alpha + psum;
        mrun = mnew;
#pragma unroll
        for (int i = 0; i < 16; i++) O[i] *= alpha;
        *(float4*)&Ps[r][dp * 8]     = *(float4*)&p[0];
        *(float4*)&Ps[r][dp * 8 + 4] = *(float4*)&p[4];
        __syncthreads();

        // O += P * V   (thread owns d = dp*16 .. dp*16+15)
#pragma unroll 4
        for (int c4 = 0; c4 < KT; c4 += 4) {
            float pv[4];
            *(float4*)&pv[0] = *(const float4*)&Ps[r][c4];
#pragma unroll
            for (int u = 0; u < 4; u++) {
                float vv[16];
                *(float4*)&vv[0]  = *(const float4*)&Vs[c4 + u][dp * 16];
                *(float4*)&vv[4]  = *(const float4*)&Vs[c4 + u][dp * 16 + 4];
                *(float4*)&vv[8]  = *(const float4*)&Vs[c4 + u][dp * 16 + 8];
                *(float4*)&vv[12] = *(const float4*)&Vs[c4 + u][dp * 16 + 12];
#pragma unroll
                for (int i = 0; i < 16; i++) O[i] += pv[u] * vv[i];
            }
        }
    }

    const float inv = 1.0f / lrun;
    float* dst = ctx + ((size_t)(b * SEQ + q0 + r)) * HID + hh * HD + dp * 16;
#pragma unroll
    for (int j = 0; j < 16; j += 4) {
        float4 o;
        o.x = O[j + 0] * inv; o.y = O[j + 1] * inv;
        o.z = O[j + 2] * inv; o.w = O[j + 3] * inv;
        *(float4*)(dst + j) = o;
    }
}

// ---------------------------------------------------------------------------
extern "C" void kernel_launch(void* const* d_in, const int* in_sizes, int n_in,
                              void* d_out, int out_size, void* d_ws, size_t ws_size,
                              hipStream_t stream)
{
    const float* hs    = (const float*)d_in[0];
    const float* mask  = (const float*)d_in[1];
    const float* Wq    = (const float*)d_in[2];
    const float* bq    = (const float*)d_in[3];
    const float* Wk    = (const float*)d_in[4];
    const float* bk    = (const float*)d_in[5];
    const float* Wv    = (const float*)d_in[6];
    const float* bv    = (const float*)d_in[7];
    const float* Wd    = (const float*)d_in[8];
    const float* bd    = (const float*)d_in[9];
    const float* gamma = (const float*)d_in[10];
    const float* beta  = (const float*)d_in[11];
    float* out = (float*)d_out;

    const size_t NE = (size_t)MROWS * HID;   // 4 Mi elements
    float* ws  = (float*)d_ws;
    float* h   = ws;            // [MROWS, HID]
    float* q   = ws + 1 * NE;   // [B, NH, S, HD]
    float* kbf = ws + 2 * NE;
    float* vbf = ws + 3 * NE;
    float* ctx = ws + 4 * NE;   // [MROWS, HID]

    ln_kernel<<<MROWS, 256, 0, stream>>>(hs, gamma, beta, h);

    dim3 gg(HID / BN, MROWS / BM);   // (8, 32)
    gemm_bias<<<gg, 256, 0, stream>>>(h, Wq, bq, q,   MROWS, HID, HID, 1);
    gemm_bias<<<gg, 256, 0, stream>>>(h, Wk, bk, kbf, MROWS, HID, HID, 1);
    gemm_bias<<<gg, 256, 0, stream>>>(h, Wv, bv, vbf, MROWS, HID, HID, 1);

    dim3 ga(SEQ / 64, NH, BATCH);    // (32, 16, 2)
    attn_kernel<<<ga, 256, 0, stream>>>(q, kbf, vbf, mask, ctx);

    gemm_bias<<<gg, 256, 0, stream>>>(ctx, Wd, bd, out, MROWS, HID, HID, 0);
}

// Round 2
// 672.129 us; speedup vs baseline: 2.0503x; 2.0503x over previous
//
#include <hip/hip_runtime.h>
#include <math.h>

#define BATCH 2
#define SEQ   2048
#define HID   1024
#define NH    16
#define HD    64
#define MROWS (BATCH * SEQ)   // 4096

typedef unsigned short u16;
typedef short bf16x8 __attribute__((ext_vector_type(8)));
typedef float f32x4  __attribute__((ext_vector_type(4)));

static __device__ __forceinline__ u16 f2bf(float f) {
    union { float f; unsigned int u; } v; v.f = f;
    unsigned int r = (v.u + 0x7FFF + ((v.u >> 16) & 1)) >> 16;  // RNE
    return (u16)r;
}

static __device__ __forceinline__ f32x4 mfma16(bf16x8 a, bf16x8 b, f32x4 c) {
    return __builtin_amdgcn_mfma_f32_16x16x32_bf16(a, b, c, 0, 0, 0);
}

// ---------------------------------------------------------------------------
// LayerNorm: one block per row, 256 threads, float4 per thread.
// ---------------------------------------------------------------------------
__global__ __launch_bounds__(256) void ln_kernel(const float* __restrict__ x,
                                                 const float* __restrict__ gamma,
                                                 const float* __restrict__ beta,
                                                 float* __restrict__ h)
{
    const int row = blockIdx.x;
    const int t = threadIdx.x;
    const float4 xv = ((const float4*)(x + (size_t)row * HID))[t];
    float s  = xv.x + xv.y + xv.z + xv.w;
    float ss = xv.x * xv.x + xv.y * xv.y + xv.z * xv.z + xv.w * xv.w;
#pragma unroll
    for (int off = 32; off > 0; off >>= 1) {
        s  += __shfl_down(s, off);
        ss += __shfl_down(ss, off);
    }
    __shared__ float red[8];
    const int wid = t >> 6;
    if ((t & 63) == 0) { red[wid] = s; red[4 + wid] = ss; }
    __syncthreads();
    s  = red[0] + red[1] + red[2] + red[3];
    ss = red[4] + red[5] + red[6] + red[7];
    const float mu   = s * (1.0f / HID);
    const float var  = ss * (1.0f / HID) - mu * mu;
    const float rstd = rsqrtf(var + 1e-12f);
    const float4 g  = ((const float4*)gamma)[t];
    const float4 bb = ((const float4*)beta)[t];
    float4 o;
    o.x = (xv.x - mu) * rstd * g.x + bb.x;
    o.y = (xv.y - mu) * rstd * g.y + bb.y;
    o.z = (xv.z - mu) * rstd * g.z + bb.z;
    o.w = (xv.w - mu) * rstd * g.w + bb.w;
    ((float4*)(h + (size_t)row * HID))[t] = o;
}

// ---------------------------------------------------------------------------
// GEMM: C = A[M,K] * W[N,K]^T + bias.  fp32 compute.
// mode 0: fp32 C[M,N]
// mode 1: bf16 C in [B,NH,S,HD]   (q, k)
// mode 2: bf16 C in [B,NH,HD,S]   (v transposed)
// ---------------------------------------------------------------------------
#define BM 128
#define BN 128
#define BK 16
#define LDT 132

__global__ __launch_bounds__(256) void gemm_bias(const float* __restrict__ A,
                                                 const float* __restrict__ W,
                                                 const float* __restrict__ bias,
                                                 void* __restrict__ Cv,
                                                 int M, int N, int K, int mode)
{
    __shared__ float As[BK][LDT];
    __shared__ float Ws[BK][LDT];
    const int t  = threadIdx.x;
    const int tx = t & 15;
    const int ty = t >> 4;
    const int bm = blockIdx.y * BM;
    const int bn = blockIdx.x * BN;

    float acc[8][8];
#pragma unroll
    for (int i = 0; i < 8; i++)
#pragma unroll
        for (int j = 0; j < 8; j++) acc[i][j] = 0.0f;

    const int lrow = t >> 1;
    const int lk   = (t & 1) * 8;
    const float* Ap = A + (size_t)(bm + lrow) * K + lk;
    const float* Wp = W + (size_t)(bn + lrow) * K + lk;

    for (int k0 = 0; k0 < K; k0 += BK) {
        const float4 a0 = *(const float4*)(Ap + k0);
        const float4 a1 = *(const float4*)(Ap + k0 + 4);
        const float4 w0 = *(const float4*)(Wp + k0);
        const float4 w1 = *(const float4*)(Wp + k0 + 4);
        __syncthreads();
        As[lk + 0][lrow] = a0.x; As[lk + 1][lrow] = a0.y;
        As[lk + 2][lrow] = a0.z; As[lk + 3][lrow] = a0.w;
        As[lk + 4][lrow] = a1.x; As[lk + 5][lrow] = a1.y;
        As[lk + 6][lrow] = a1.z; As[lk + 7][lrow] = a1.w;
        Ws[lk + 0][lrow] = w0.x; Ws[lk + 1][lrow] = w0.y;
        Ws[lk + 2][lrow] = w0.z; Ws[lk + 3][lrow] = w0.w;
        Ws[lk + 4][lrow] = w1.x; Ws[lk + 5][lrow] = w1.y;
        Ws[lk + 6][lrow] = w1.z; Ws[lk + 7][lrow] = w1.w;
        __syncthreads();
#pragma unroll
        for (int kk = 0; kk < BK; kk++) {
            float a[8], w[8];
            *(float4*)&a[0] = *(const float4*)&As[kk][ty * 8];
            *(float4*)&a[4] = *(const float4*)&As[kk][ty * 8 + 4];
            *(float4*)&w[0] = *(const float4*)&Ws[kk][tx * 8];
            *(float4*)&w[4] = *(const float4*)&Ws[kk][tx * 8 + 4];
#pragma unroll
            for (int i = 0; i < 8; i++)
#pragma unroll
                for (int j = 0; j < 8; j++) acc[i][j] += a[i] * w[j];
        }
    }

    float bvals[8];
#pragma unroll
    for (int j = 0; j < 8; j++) bvals[j] = bias[bn + tx * 8 + j];

    if (mode == 0) {
        float* C = (float*)Cv;
#pragma unroll
        for (int i = 0; i < 8; i++) {
            const int m = bm + ty * 8 + i;
            float* dst = C + (size_t)m * N + bn + tx * 8;
            float4 o0, o1;
            o0.x = acc[i][0] + bvals[0]; o0.y = acc[i][1] + bvals[1];
            o0.z = acc[i][2] + bvals[2]; o0.w = acc[i][3] + bvals[3];
            o1.x = acc[i][4] + bvals[4]; o1.y = acc[i][5] + bvals[5];
            o1.z = acc[i][6] + bvals[6]; o1.w = acc[i][7] + bvals[7];
            *(float4*)dst       = o0;
            *(float4*)(dst + 4) = o1;
        }
    } else if (mode == 1) {
        u16* C = (u16*)Cv;
        const int n0 = bn + tx * 8;
        const int hh = n0 >> 6;
        const int d0 = n0 & 63;
#pragma unroll
        for (int i = 0; i < 8; i++) {
            const int m  = bm + ty * 8 + i;
            const int bI = m >> 11;
            const int sI = m & (SEQ - 1);
            u16* dst = C + ((size_t)(bI * NH + hh) * SEQ + sI) * HD + d0;
            union { u16 s[8]; uint4 v; } tmp;
#pragma unroll
            for (int j = 0; j < 8; j++) tmp.s[j] = f2bf(acc[i][j] + bvals[j]);
            *(uint4*)dst = tmp.v;
        }
    } else {
        u16* C = (u16*)Cv;
        const int n0 = bn + tx * 8;
        const int hh = n0 >> 6;
        const int d0 = n0 & 63;
        const int m0 = bm + ty * 8;
        const int bI = m0 >> 11;
        const int sI = m0 & (SEQ - 1);
#pragma unroll
        for (int j = 0; j < 8; j++) {
            union { u16 s[8]; uint4 v; } tmp;
#pragma unroll
            for (int i = 0; i < 8; i++) tmp.s[i] = f2bf(acc[i][j] + bvals[j]);
            u16* dst = C + ((size_t)(bI * NH + hh) * HD + d0 + j) * SEQ + sI;
            *(uint4*)dst = tmp.v;
        }
    }
}

// ---------------------------------------------------------------------------
// MFMA flash attention.  Block = 128 q rows of one (b,h); 4 waves; wave owns
// 32 q.  KV tile 64.  Computes S^T = K·Q^T and O^T = V^T·P^T so all MFMA
// fragments are contiguous 16B reads.  P is per-wave-private in LDS.
// ---------------------------------------------------------------------------
__global__ __launch_bounds__(256) void attn_mfma(const u16* __restrict__ qb,
                                                 const u16* __restrict__ kb,
                                                 const u16* __restrict__ vtb,
                                                 const float* __restrict__ maskg,
                                                 float* __restrict__ ctx)
{
    // smem layout (bytes):
    //   [0,      9216)  Ks  [64][72] u16
    //   [9216,  18432)  Vts [64][72] u16
    //   [18432, 36864)  Pq  4 waves x [32][72] u16
    //   [36864, 37120)  Ms  [64] float
    // epilogue reuses [0, 34816) as 4 waves x float[32][68]
    __shared__ __align__(16) char smem[37120];
    u16 (*Ks)[72]  = (u16(*)[72])(smem);
    u16 (*Vts)[72] = (u16(*)[72])(smem + 9216);
    u16 (*Pqw)[72] = (u16(*)[72])(smem + 18432 + (threadIdx.x >> 6) * 4608);
    float* Ms = (float*)(smem + 36864);

    const int t    = threadIdx.x;
    const int wave = t >> 6;
    const int lane = t & 63;
    const int l15  = lane & 15;
    const int quad = lane >> 4;

    const int b  = blockIdx.z;
    const int hh = blockIdx.y;
    const int q0 = blockIdx.x * 128;
    const size_t headoff = (size_t)(b * NH + hh) * SEQ * HD;
    const u16* kbase = kb  + headoff;
    const u16* vbase = vtb + headoff;

    // Q fragments (B-operand): lane holds Q[q = wq + nt*16 + l15][k = ks*32 + quad*8 + j]
    bf16x8 Qf[2][2];
    {
        const int qrow = q0 + wave * 32 + l15;
#pragma unroll
        for (int nt = 0; nt < 2; nt++)
#pragma unroll
            for (int ks = 0; ks < 2; ks++)
                Qf[nt][ks] = *(const bf16x8*)(qb + headoff +
                    (size_t)(qrow + nt * 16) * HD + ks * 32 + quad * 8);
    }

    f32x4 O[4][2];
#pragma unroll
    for (int mt = 0; mt < 4; mt++)
#pragma unroll
        for (int nt = 0; nt < 2; nt++) O[mt][nt] = (f32x4)0.0f;
    float mrun[2] = {-INFINITY, -INFINITY};
    float lrun[2] = {0.0f, 0.0f};

    const int skv = t >> 2;          // staging row 0..63
    const int sch = (t & 3) * 16;    // staging 16-elem chunk

    for (int c0 = 0; c0 < SEQ; c0 += 64) {
        __syncthreads();
        // stage K tile [kv][d] and V^T tile [d][kv], both bf16
        {
            const u16* ksrc = kbase + (size_t)(c0 + skv) * HD + sch;
            *(uint4*)&Ks[skv][sch]     = *(const uint4*)(ksrc);
            *(uint4*)&Ks[skv][sch + 8] = *(const uint4*)(ksrc + 8);
            const u16* vsrc = vbase + (size_t)skv * SEQ + c0 + sch;
            *(uint4*)&Vts[skv][sch]     = *(const uint4*)(vsrc);
            *(uint4*)&Vts[skv][sch + 8] = *(const uint4*)(vsrc + 8);
            if (t < 64) Ms[t] = -1000.0f * (1.0f - maskg[b * SEQ + c0 + t]);
        }
        __syncthreads();

        // S^T tiles: D[m=kv][n=q] = sum_d K[kv][d] * Q[q][d]
        f32x4 St[4][2];
#pragma unroll
        for (int mt = 0; mt < 4; mt++) {
            const bf16x8 ka0 = *(const bf16x8*)&Ks[mt * 16 + l15][quad * 8];
            const bf16x8 ka1 = *(const bf16x8*)&Ks[mt * 16 + l15][32 + quad * 8];
#pragma unroll
            for (int nt = 0; nt < 2; nt++) {
                f32x4 acc = (f32x4)0.0f;
                acc = mfma16(ka0, Qf[nt][0], acc);
                acc = mfma16(ka1, Qf[nt][1], acc);
                St[mt][nt] = acc;
            }
        }

        // additive mask per kv row (lane's rows: mt*16 + quad*4 + r)
        f32x4 mv[4];
#pragma unroll
        for (int mt = 0; mt < 4; mt++)
            mv[mt] = *(const f32x4*)&Ms[mt * 16 + quad * 4];

        // online softmax per q column (col = l15 within ntile)
#pragma unroll
        for (int nt = 0; nt < 2; nt++) {
            float mx = -INFINITY;
#pragma unroll
            for (int mt = 0; mt < 4; mt++)
#pragma unroll
                for (int r = 0; r < 4; r++) {
                    float v = St[mt][nt][r] * 0.125f + mv[mt][r];
                    St[mt][nt][r] = v;
                    mx = fmaxf(mx, v);
                }
            mx = fmaxf(mx, __shfl_xor(mx, 16));
            mx = fmaxf(mx, __shfl_xor(mx, 32));
            const float mnew  = fmaxf(mrun[nt], mx);
            const float alpha = __expf(mrun[nt] - mnew);
            mrun[nt] = mnew;
            float ps = 0.0f;
#pragma unroll
            for (int mt = 0; mt < 4; mt++)
#pragma unroll
                for (int r = 0; r < 4; r++) {
                    float p = __expf(St[mt][nt][r] - mnew);
                    St[mt][nt][r] = p;
                    ps += p;
                }
            ps += __shfl_xor(ps, 16);
            ps += __shfl_xor(ps, 32);
            lrun[nt] = lrun[nt] * alpha + ps;
#pragma unroll
            for (int mt = 0; mt < 4; mt++) O[mt][nt] *= alpha;
            // pack 4 consecutive-kv probs -> 8B LDS write (P in [q][kv])
#pragma unroll
            for (int mt = 0; mt < 4; mt++) {
                union { u16 s[4]; uint2 v; } pk;
#pragma unroll
                for (int r = 0; r < 4; r++) pk.s[r] = f2bf(St[mt][nt][r]);
                *(uint2*)&Pqw[nt * 16 + l15][mt * 16 + quad * 4] = pk.v;
            }
        }

        // P fragments (B-operand): lane holds P[q = l15 + nt*16][kv = ks*32 + quad*8 + j]
        bf16x8 Pb[2][2];
#pragma unroll
        for (int nt = 0; nt < 2; nt++)
#pragma unroll
            for (int ks = 0; ks < 2; ks++)
                Pb[nt][ks] = *(const bf16x8*)&Pqw[nt * 16 + l15][ks * 32 + quad * 8];

        // O^T tiles: D[m=d][n=q] += sum_kv V[kv][d] * P[q][kv]
#pragma unroll
        for (int mt = 0; mt < 4; mt++) {
            const bf16x8 va0 = *(const bf16x8*)&Vts[mt * 16 + l15][quad * 8];
            const bf16x8 va1 = *(const bf16x8*)&Vts[mt * 16 + l15][32 + quad * 8];
#pragma unroll
            for (int nt = 0; nt < 2; nt++) {
                O[mt][nt] = mfma16(va0, Pb[nt][0], O[mt][nt]);
                O[mt][nt] = mfma16(va1, Pb[nt][1], O[mt][nt]);
            }
        }
    }

    // epilogue: O^T -> [q][d] via LDS, then coalesced global store
    __syncthreads();
    float* Ot = (float*)smem + wave * (32 * 68);
    const float linv0 = 1.0f / lrun[0];
    const float linv1 = 1.0f / lrun[1];
#pragma unroll
    for (int mt = 0; mt < 4; mt++)
#pragma unroll
        for (int nt = 0; nt < 2; nt++) {
            const float li = nt ? linv1 : linv0;
            f32x4 v = O[mt][nt] * li;
            *(f32x4*)(Ot + (nt * 16 + l15) * 68 + mt * 16 + quad * 4) = v;
        }
    __syncthreads();
    {
        const int qlocal = lane >> 1;
        const int half   = lane & 1;
        const float* srcp = Ot + qlocal * 68 + half * 32;
        float* dstp = ctx + (size_t)(b * SEQ + q0 + wave * 32 + qlocal) * HID
                          + hh * 64 + half * 32;
#pragma unroll
        for (int j = 0; j < 8; j++)
            *(f32x4*)(dstp + j * 4) = *(const f32x4*)(srcp + j * 4);
    }
}

// ---------------------------------------------------------------------------
extern "C" void kernel_launch(void* const* d_in, const int* in_sizes, int n_in,
                              void* d_out, int out_size, void* d_ws, size_t ws_size,
                              hipStream_t stream)
{
    const float* hs    = (const float*)d_in[0];
    const float* mask  = (const float*)d_in[1];
    const float* Wq    = (const float*)d_in[2];
    const float* bq    = (const float*)d_in[3];
    const float* Wk    = (const float*)d_in[4];
    const float* bk    = (const float*)d_in[5];
    const float* Wv    = (const float*)d_in[6];
    const float* bv    = (const float*)d_in[7];
    const float* Wd    = (const float*)d_in[8];
    const float* bd    = (const float*)d_in[9];
    const float* gamma = (const float*)d_in[10];
    const float* beta  = (const float*)d_in[11];
    float* out = (float*)d_out;

    const size_t NE = (size_t)MROWS * HID;
    float* ws  = (float*)d_ws;
    float* h   = ws;                      // fp32 [MROWS, HID]
    float* ctx = ws + NE;                 // fp32 [MROWS, HID]
    u16* qbb = (u16*)(ws + 2 * NE);       // bf16 [B,NH,S,HD]
    u16* kbb = qbb + NE;                  // bf16 [B,NH,S,HD]
    u16* vtb = kbb + NE;                  // bf16 [B,NH,HD,S]

    ln_kernel<<<MROWS, 256, 0, stream>>>(hs, gamma, beta, h);

    dim3 gg(HID / BN, MROWS / BM);   // (8, 32)
    gemm_bias<<<gg, 256, 0, stream>>>(h, Wq, bq, qbb, MROWS, HID, HID, 1);
    gemm_bias<<<gg, 256, 0, stream>>>(h, Wk, bk, kbb, MROWS, HID, HID, 1);
    gemm_bias<<<gg, 256, 0, stream>>>(h, Wv, bv, vtb, MROWS, HID, HID, 2);

    dim3 ga(SEQ / 128, NH, BATCH);   // (16, 16, 2)
    attn_mfma<<<ga, 256, 0, stream>>>(qbb, kbb, vtb, mask, ctx);

    gemm_bias<<<gg, 256, 0, stream>>>(ctx, Wd, bd, out, MROWS, HID, HID, 0);
}

// Round 3
// 256.421 us; speedup vs baseline: 5.3742x; 2.6212x over previous
//
#include <hip/hip_runtime.h>
#include <math.h>

#define BATCH 2
#define SEQ   2048
#define HID   1024
#define NH    16
#define HD    64
#define MROWS (BATCH * SEQ)   // 4096

typedef unsigned short u16;
typedef short bf16x8 __attribute__((ext_vector_type(8)));
typedef float f32x4  __attribute__((ext_vector_type(4)));

static __device__ __forceinline__ u16 f2bf(float f) {
    union { float f; unsigned int u; } v; v.f = f;
    unsigned int r = (v.u + 0x7FFF + ((v.u >> 16) & 1)) >> 16;  // RNE
    return (u16)r;
}

static __device__ __forceinline__ f32x4 mfma16(bf16x8 a, bf16x8 b, f32x4 c) {
    return __builtin_amdgcn_mfma_f32_16x16x32_bf16(a, b, c, 0, 0, 0);
}

// global -> LDS async copy, 16 B per lane.  LDS dest must be the wave-uniform
// base; HW adds lane*16.  AS3 pointers are 32-bit = LDS offset (low 32 bits of
// the generic aperture address), so the int-truncation cast is the correct CK
// idiom.
static __device__ __forceinline__ void ldsload16(const void* g, void* l) {
    __builtin_amdgcn_global_load_lds(
        (const __attribute__((address_space(1))) void*)(unsigned long long)(uintptr_t)g,
        (__attribute__((address_space(3))) void*)(unsigned int)(uintptr_t)l,
        16, 0, 0);
}

// ---------------------------------------------------------------------------
// LayerNorm: one block per row, 256 threads, float4 per thread.  bf16 out.
// ---------------------------------------------------------------------------
__global__ __launch_bounds__(256) void ln_kernel(const float* __restrict__ x,
                                                 const float* __restrict__ gamma,
                                                 const float* __restrict__ beta,
                                                 u16* __restrict__ h)
{
    const int row = blockIdx.x;
    const int t = threadIdx.x;
    const float4 xv = ((const float4*)(x + (size_t)row * HID))[t];
    float s  = xv.x + xv.y + xv.z + xv.w;
    float ss = xv.x * xv.x + xv.y * xv.y + xv.z * xv.z + xv.w * xv.w;
#pragma unroll
    for (int off = 32; off > 0; off >>= 1) {
        s  += __shfl_down(s, off);
        ss += __shfl_down(ss, off);
    }
    __shared__ float red[8];
    const int wid = t >> 6;
    if ((t & 63) == 0) { red[wid] = s; red[4 + wid] = ss; }
    __syncthreads();
    s  = red[0] + red[1] + red[2] + red[3];
    ss = red[4] + red[5] + red[6] + red[7];
    const float mu   = s * (1.0f / HID);
    const float var  = ss * (1.0f / HID) - mu * mu;
    const float rstd = rsqrtf(var + 1e-12f);
    const float4 g  = ((const float4*)gamma)[t];
    const float4 bb = ((const float4*)beta)[t];
    union { u16 s[4]; uint2 v; } p;
    p.s[0] = f2bf((xv.x - mu) * rstd * g.x + bb.x);
    p.s[1] = f2bf((xv.y - mu) * rstd * g.y + bb.y);
    p.s[2] = f2bf((xv.z - mu) * rstd * g.z + bb.z);
    p.s[3] = f2bf((xv.w - mu) * rstd * g.w + bb.w);
    ((uint2*)(h + (size_t)row * HID))[t] = p.v;
}

// ---------------------------------------------------------------------------
// Cast the 4 weight matrices (each HID*HID fp32) to bf16.  4096 blocks.
// ---------------------------------------------------------------------------
__global__ __launch_bounds__(256) void cast_w(const float* __restrict__ w0,
                                              const float* __restrict__ w1,
                                              const float* __restrict__ w2,
                                              const float* __restrict__ w3,
                                              u16* o0, u16* o1, u16* o2, u16* o3)
{
    const int blk = blockIdx.x;
    const int which = blk >> 10;
    const int lb = blk & 1023;
    const float* src = which == 0 ? w0 : which == 1 ? w1 : which == 2 ? w2 : w3;
    u16* dst = which == 0 ? o0 : which == 1 ? o1 : which == 2 ? o2 : o3;
    const int idx = (lb * 256 + threadIdx.x) * 4;
    const float4 f = *(const float4*)(src + idx);
    union { u16 s[4]; uint2 v; } p;
    p.s[0] = f2bf(f.x); p.s[1] = f2bf(f.y); p.s[2] = f2bf(f.z); p.s[3] = f2bf(f.w);
    *(uint2*)(dst + idx) = p.v;
}

// ---------------------------------------------------------------------------
// MFMA GEMM core: 128x128 tile, BK=32, 4 waves in 2x2, wave = 64x64 (4x4
// 16x16x32 MFMA tiles).  A[M,K], B[N,K] row-major bf16 (C = A * B^T).
// m97 structure: global_load_lds width 16, single-buffered LDS, 2 barriers.
// ---------------------------------------------------------------------------
static __device__ __forceinline__ void gemm_core(const u16* __restrict__ A,
                                                 const u16* __restrict__ B,
                                                 int K, int bm, int bn,
                                                 u16* As, u16* Bs,
                                                 int wave, int lane,
                                                 f32x4 acc[4][4])
{
    const int l15  = lane & 15;
    const int quad = lane >> 4;
    const int wm = (wave >> 1) * 64;
    const int wn = (wave & 1) * 64;

    // staging: tile = [128 rows][32 bf16] = 512 x 16B chunks; chunk c -> row
    // c>>2, k-chunk (c&3)*8.  Wave w stages chunks [w*64, w*64+64) and +256.
    const int c1 = wave * 64 + lane;
    const int c2 = c1 + 256;
    const u16* A1 = A + (size_t)(bm + (c1 >> 2)) * K + (c1 & 3) * 8;
    const u16* A2 = A + (size_t)(bm + (c2 >> 2)) * K + (c2 & 3) * 8;
    const u16* B1 = B + (size_t)(bn + (c1 >> 2)) * K + (c1 & 3) * 8;
    const u16* B2 = B + (size_t)(bn + (c2 >> 2)) * K + (c2 & 3) * 8;
    u16* lA1 = As + wave * 512;
    u16* lA2 = As + 2048 + wave * 512;
    u16* lB1 = Bs + wave * 512;
    u16* lB2 = Bs + 2048 + wave * 512;

    for (int k0 = 0; k0 < K; k0 += 32) {
        __syncthreads();
        ldsload16(A1 + k0, lA1);
        ldsload16(A2 + k0, lA2);
        ldsload16(B1 + k0, lB1);
        ldsload16(B2 + k0, lB2);
        __syncthreads();
        bf16x8 af[4], bfr[4];
#pragma unroll
        for (int mt = 0; mt < 4; mt++)
            af[mt] = *(const bf16x8*)&As[(wm + mt * 16 + l15) * 32 + quad * 8];
#pragma unroll
        for (int nt = 0; nt < 4; nt++)
            bfr[nt] = *(const bf16x8*)&Bs[(wn + nt * 16 + l15) * 32 + quad * 8];
#pragma unroll
        for (int mt = 0; mt < 4; mt++)
#pragma unroll
            for (int nt = 0; nt < 4; nt++)
                acc[mt][nt] = mfma16(af[mt], bfr[nt], acc[mt][nt]);
    }
}

// ---------------------------------------------------------------------------
// Fused QKV.  Blocks 0..255: q = h*Wq^T (head layout).  256..511: k.
// 512..767: V' = Wv * h^T -> row-major [HID][MROWS] bf16 (transposed V).
// ---------------------------------------------------------------------------
__global__ __launch_bounds__(256) void qkv_gemm(const u16* __restrict__ h,
                                                const u16* __restrict__ wq,
                                                const u16* __restrict__ wk,
                                                const u16* __restrict__ wv,
                                                const float* __restrict__ bq,
                                                const float* __restrict__ bk,
                                                const float* __restrict__ bv,
                                                u16* __restrict__ qo,
                                                u16* __restrict__ ko,
                                                u16* __restrict__ vo)
{
    __shared__ u16 As[4096];
    __shared__ u16 Bs[4096];
    const int blk  = blockIdx.x;
    const int wave = threadIdx.x >> 6;
    const int lane = threadIdx.x & 63;
    const int l15  = lane & 15;
    const int quad = lane >> 4;
    const int wm = (wave >> 1) * 64;
    const int wn = (wave & 1) * 64;

    f32x4 acc[4][4];
#pragma unroll
    for (int mt = 0; mt < 4; mt++)
#pragma unroll
        for (int nt = 0; nt < 4; nt++) acc[mt][nt] = (f32x4)0.0f;

    if (blk < 512) {
        const u16* W     = (blk < 256) ? wq : wk;
        const float* bia = (blk < 256) ? bq : bk;
        u16* out         = (blk < 256) ? qo : ko;
        const int local = blk & 255;
        const int bm = (local >> 3) * 128;   // token rows
        const int bn = (local & 7) * 128;    // output features
        gemm_core(h, W, HID, bm, bn, As, Bs, wave, lane, acc);

        float bv4[4];
#pragma unroll
        for (int nt = 0; nt < 4; nt++) bv4[nt] = bia[bn + wn + nt * 16 + l15];
#pragma unroll
        for (int mt = 0; mt < 4; mt++)
#pragma unroll
            for (int r = 0; r < 4; r++) {
                const int m  = bm + wm + mt * 16 + quad * 4 + r;
                const int bI = m >> 11;
                const int sI = m & (SEQ - 1);
#pragma unroll
                for (int nt = 0; nt < 4; nt++) {
                    const int n  = bn + wn + nt * 16 + l15;
                    const int hh = n >> 6;
                    const int d  = n & 63;
                    out[(((size_t)(bI * NH + hh) * SEQ + sI) << 6) + d] =
                        f2bf(acc[mt][nt][r] + bv4[nt]);
                }
            }
    } else {
        const int local = blk - 512;
        const int bm = (local & 7) * 128;    // Wv rows (features)
        const int bn = (local >> 3) * 128;   // token rows
        gemm_core(wv, h, HID, bm, bn, As, Bs, wave, lane, acc);

#pragma unroll
        for (int mt = 0; mt < 4; mt++) {
            const f32x4 bm4 = *(const f32x4*)&bv[bm + wm + mt * 16 + quad * 4];
#pragma unroll
            for (int r = 0; r < 4; r++) {
                const int row = bm + wm + mt * 16 + quad * 4 + r;
#pragma unroll
                for (int nt = 0; nt < 4; nt++) {
                    const int col = bn + wn + nt * 16 + l15;
                    vo[(size_t)row * MROWS + col] = f2bf(acc[mt][nt][r] + bm4[r]);
                }
            }
        }
    }
}

// ---------------------------------------------------------------------------
// Output projection: out = ctx * Wd^T + bd, fp32 out [MROWS][HID].
// ---------------------------------------------------------------------------
__global__ __launch_bounds__(256) void out_gemm(const u16* __restrict__ ctx,
                                                const u16* __restrict__ wd,
                                                const float* __restrict__ bd,
                                                float* __restrict__ out)
{
    __shared__ u16 As[4096];
    __shared__ u16 Bs[4096];
    const int blk  = blockIdx.x;
    const int wave = threadIdx.x >> 6;
    const int lane = threadIdx.x & 63;
    const int l15  = lane & 15;
    const int quad = lane >> 4;
    const int wm = (wave >> 1) * 64;
    const int wn = (wave & 1) * 64;
    const int bm = (blk >> 3) * 128;
    const int bn = (blk & 7) * 128;

    f32x4 acc[4][4];
#pragma unroll
    for (int mt = 0; mt < 4; mt++)
#pragma unroll
        for (int nt = 0; nt < 4; nt++) acc[mt][nt] = (f32x4)0.0f;

    gemm_core(ctx, wd, HID, bm, bn, As, Bs, wave, lane, acc);

    float bv4[4];
#pragma unroll
    for (int nt = 0; nt < 4; nt++) bv4[nt] = bd[bn + wn + nt * 16 + l15];
#pragma unroll
    for (int mt = 0; mt < 4; mt++)
#pragma unroll
        for (int r = 0; r < 4; r++) {
            const int m = bm + wm + mt * 16 + quad * 4 + r;
#pragma unroll
            for (int nt = 0; nt < 4; nt++) {
                const int n = bn + wn + nt * 16 + l15;
                out[(size_t)m * HID + n] = acc[mt][nt][r] + bv4[nt];
            }
        }
}

// ---------------------------------------------------------------------------
// MFMA flash attention (unchanged core).  V is now [HID][MROWS] bf16
// (row = hh*64+d, col = b*SEQ+s); ctx written bf16 [MROWS][HID].
// ---------------------------------------------------------------------------
__global__ __launch_bounds__(256) void attn_mfma(const u16* __restrict__ qb,
                                                 const u16* __restrict__ kb,
                                                 const u16* __restrict__ vtb,
                                                 const float* __restrict__ maskg,
                                                 u16* __restrict__ ctx)
{
    __shared__ __align__(16) char smem[37120];
    u16 (*Ks)[72]  = (u16(*)[72])(smem);
    u16 (*Vts)[72] = (u16(*)[72])(smem + 9216);
    u16 (*Pqw)[72] = (u16(*)[72])(smem + 18432 + (threadIdx.x >> 6) * 4608);
    float* Ms = (float*)(smem + 36864);

    const int t    = threadIdx.x;
    const int wave = t >> 6;
    const int lane = t & 63;
    const int l15  = lane & 15;
    const int quad = lane >> 4;

    const int b  = blockIdx.z;
    const int hh = blockIdx.y;
    const int q0 = blockIdx.x * 128;
    const size_t headoff = (size_t)(b * NH + hh) * SEQ * HD;
    const u16* kbase = kb + headoff;
    const u16* vbase = vtb + (size_t)(hh * HD) * MROWS + b * SEQ;

    bf16x8 Qf[2][2];
    {
        const int qrow = q0 + wave * 32 + l15;
#pragma unroll
        for (int nt = 0; nt < 2; nt++)
#pragma unroll
            for (int ks = 0; ks < 2; ks++)
                Qf[nt][ks] = *(const bf16x8*)(qb + headoff +
                    (size_t)(qrow + nt * 16) * HD + ks * 32 + quad * 8);
    }

    f32x4 O[4][2];
#pragma unroll
    for (int mt = 0; mt < 4; mt++)
#pragma unroll
        for (int nt = 0; nt < 2; nt++) O[mt][nt] = (f32x4)0.0f;
    float mrun[2] = {-INFINITY, -INFINITY};
    float lrun[2] = {0.0f, 0.0f};

    const int skv = t >> 2;
    const int sch = (t & 3) * 16;

    for (int c0 = 0; c0 < SEQ; c0 += 64) {
        __syncthreads();
        {
            const u16* ksrc = kbase + (size_t)(c0 + skv) * HD + sch;
            *(uint4*)&Ks[skv][sch]     = *(const uint4*)(ksrc);
            *(uint4*)&Ks[skv][sch + 8] = *(const uint4*)(ksrc + 8);
            const u16* vsrc = vbase + (size_t)skv * MROWS + c0 + sch;
            *(uint4*)&Vts[skv][sch]     = *(const uint4*)(vsrc);
            *(uint4*)&Vts[skv][sch + 8] = *(const uint4*)(vsrc + 8);
            if (t < 64) Ms[t] = -1000.0f * (1.0f - maskg[b * SEQ + c0 + t]);
        }
        __syncthreads();

        f32x4 St[4][2];
#pragma unroll
        for (int mt = 0; mt < 4; mt++) {
            const bf16x8 ka0 = *(const bf16x8*)&Ks[mt * 16 + l15][quad * 8];
            const bf16x8 ka1 = *(const bf16x8*)&Ks[mt * 16 + l15][32 + quad * 8];
#pragma unroll
            for (int nt = 0; nt < 2; nt++) {
                f32x4 a = (f32x4)0.0f;
                a = mfma16(ka0, Qf[nt][0], a);
                a = mfma16(ka1, Qf[nt][1], a);
                St[mt][nt] = a;
            }
        }

        f32x4 mv[4];
#pragma unroll
        for (int mt = 0; mt < 4; mt++)
            mv[mt] = *(const f32x4*)&Ms[mt * 16 + quad * 4];

#pragma unroll
        for (int nt = 0; nt < 2; nt++) {
            float mx = -INFINITY;
#pragma unroll
            for (int mt = 0; mt < 4; mt++)
#pragma unroll
                for (int r = 0; r < 4; r++) {
                    float v = St[mt][nt][r] * 0.125f + mv[mt][r];
                    St[mt][nt][r] = v;
                    mx = fmaxf(mx, v);
                }
            mx = fmaxf(mx, __shfl_xor(mx, 16));
            mx = fmaxf(mx, __shfl_xor(mx, 32));
            const float mnew  = fmaxf(mrun[nt], mx);
            const float alpha = __expf(mrun[nt] - mnew);
            mrun[nt] = mnew;
            float ps = 0.0f;
#pragma unroll
            for (int mt = 0; mt < 4; mt++)
#pragma unroll
                for (int r = 0; r < 4; r++) {
                    float p = __expf(St[mt][nt][r] - mnew);
                    St[mt][nt][r] = p;
                    ps += p;
                }
            ps += __shfl_xor(ps, 16);
            ps += __shfl_xor(ps, 32);
            lrun[nt] = lrun[nt] * alpha + ps;
#pragma unroll
            for (int mt = 0; mt < 4; mt++) O[mt][nt] *= alpha;
#pragma unroll
            for (int mt = 0; mt < 4; mt++) {
                union { u16 s[4]; uint2 v; } pk;
#pragma unroll
                for (int r = 0; r < 4; r++) pk.s[r] = f2bf(St[mt][nt][r]);
                *(uint2*)&Pqw[nt * 16 + l15][mt * 16 + quad * 4] = pk.v;
            }
        }

        bf16x8 Pb[2][2];
#pragma unroll
        for (int nt = 0; nt < 2; nt++)
#pragma unroll
            for (int ks = 0; ks < 2; ks++)
                Pb[nt][ks] = *(const bf16x8*)&Pqw[nt * 16 + l15][ks * 32 + quad * 8];

#pragma unroll
        for (int mt = 0; mt < 4; mt++) {
            const bf16x8 va0 = *(const bf16x8*)&Vts[mt * 16 + l15][quad * 8];
            const bf16x8 va1 = *(const bf16x8*)&Vts[mt * 16 + l15][32 + quad * 8];
#pragma unroll
            for (int nt = 0; nt < 2; nt++) {
                O[mt][nt] = mfma16(va0, Pb[nt][0], O[mt][nt]);
                O[mt][nt] = mfma16(va1, Pb[nt][1], O[mt][nt]);
            }
        }
    }

    __syncthreads();
    float* Ot = (float*)smem + wave * (32 * 68);
    const float linv0 = 1.0f / lrun[0];
    const float linv1 = 1.0f / lrun[1];
#pragma unroll
    for (int mt = 0; mt < 4; mt++)
#pragma unroll
        for (int nt = 0; nt < 2; nt++) {
            const float li = nt ? linv1 : linv0;
            f32x4 v = O[mt][nt] * li;
            *(f32x4*)(Ot + (nt * 16 + l15) * 68 + mt * 16 + quad * 4) = v;
        }
    __syncthreads();
    {
        const int qlocal = lane >> 1;
        const int half   = lane & 1;
        const float* srcp = Ot + qlocal * 68 + half * 32;
        u16* dstp = ctx + (size_t)(b * SEQ + q0 + wave * 32 + qlocal) * HID
                        + hh * 64 + half * 32;
#pragma unroll
        for (int j = 0; j < 4; j++) {
            union { u16 s[8]; uint4 v; } p;
#pragma unroll
            for (int i = 0; i < 8; i++) p.s[i] = f2bf(srcp[j * 8 + i]);
            *(uint4*)(dstp + j * 8) = p.v;
        }
    }
}

// ---------------------------------------------------------------------------
extern "C" void kernel_launch(void* const* d_in, const int* in_sizes, int n_in,
                              void* d_out, int out_size, void* d_ws, size_t ws_size,
                              hipStream_t stream)
{
    const float* hs    = (const float*)d_in[0];
    const float* mask  = (const float*)d_in[1];
    const float* Wq    = (const float*)d_in[2];
    const float* bq    = (const float*)d_in[3];
    const float* Wk    = (const float*)d_in[4];
    const float* bk    = (const float*)d_in[5];
    const float* Wv    = (const float*)d_in[6];
    const float* bv    = (const float*)d_in[7];
    const float* Wd    = (const float*)d_in[8];
    const float* bd    = (const float*)d_in[9];
    const float* gamma = (const float*)d_in[10];
    const float* beta  = (const float*)d_in[11];
    float* out = (float*)d_out;

    const size_t NE = (size_t)MROWS * HID;   // 4 Mi elements
    u16* ws   = (u16*)d_ws;
    u16* h    = ws;                 // bf16 [MROWS][HID]
    u16* qbb  = ws + NE;            // bf16 [B,NH,S,HD]
    u16* kbb  = qbb + NE;           // bf16 [B,NH,S,HD]
    u16* vtb  = kbb + NE;           // bf16 [HID][MROWS]  (V transposed)
    u16* ctxb = vtb + NE;           // bf16 [MROWS][HID]
    u16* wqb  = ctxb + NE;          // bf16 [HID][HID] each
    u16* wkb  = wqb + HID * HID;
    u16* wvb  = wkb + HID * HID;
    u16* wdb  = wvb + HID * HID;

    ln_kernel<<<MROWS, 256, 0, stream>>>(hs, gamma, beta, h);
    cast_w<<<4096, 256, 0, stream>>>(Wq, Wk, Wv, Wd, wqb, wkb, wvb, wdb);

    qkv_gemm<<<768, 256, 0, stream>>>(h, wqb, wkb, wvb, bq, bk, bv, qbb, kbb, vtb);

    dim3 ga(SEQ / 128, NH, BATCH);   // (16, 16, 2)
    attn_mfma<<<ga, 256, 0, stream>>>(qbb, kbb, vtb, mask, ctxb);

    out_gemm<<<256, 256, 0, stream>>>(ctxb, wdb, bd, out);
}

// Round 4
// 236.841 us; speedup vs baseline: 5.8185x; 1.0827x over previous
//
#include <hip/hip_runtime.h>
#include <math.h>

#define BATCH 2
#define SEQ   2048
#define HID   1024
#define NH    16
#define HD    64
#define MROWS (BATCH * SEQ)   // 4096
#define VSTR  4160            // padded row stride of V' (avoid 8192B channel camping)

typedef unsigned short u16;
typedef short bf16x8 __attribute__((ext_vector_type(8)));
typedef float f32x4  __attribute__((ext_vector_type(4)));

#define LOG2E 1.4426950408889634f
#define C2    (0.125f * LOG2E)      // score scale folded into log2 domain
#define M2F   23.083120f            // fixed softmax shift (16 * log2e), shift-invariant

static __device__ __forceinline__ u16 f2bf(float f) {
    union { float f; unsigned int u; } v; v.f = f;
    unsigned int r = (v.u + 0x7FFF + ((v.u >> 16) & 1)) >> 16;  // RNE
    return (u16)r;
}

static __device__ __forceinline__ f32x4 mfma16(bf16x8 a, bf16x8 b, f32x4 c) {
    return __builtin_amdgcn_mfma_f32_16x16x32_bf16(a, b, c, 0, 0, 0);
}

// global -> LDS async copy, 16 B per lane; LDS dest = wave-uniform base + lane*16.
static __device__ __forceinline__ void ldsload16(const void* g, void* l) {
    __builtin_amdgcn_global_load_lds(
        (const __attribute__((address_space(1))) void*)(unsigned long long)(uintptr_t)g,
        (__attribute__((address_space(3))) void*)(unsigned int)(uintptr_t)l,
        16, 0, 0);
}

// ---------------------------------------------------------------------------
// Fused prep: blocks [0,4096) cast the 4 weight matrices to bf16;
// blocks [4096,8192) do LayerNorm rows (bf16 out).
// ---------------------------------------------------------------------------
__global__ __launch_bounds__(256) void prep_kernel(const float* __restrict__ x,
                                                   const float* __restrict__ gamma,
                                                   const float* __restrict__ beta,
                                                   u16* __restrict__ h,
                                                   const float* __restrict__ w0,
                                                   const float* __restrict__ w1,
                                                   const float* __restrict__ w2,
                                                   const float* __restrict__ w3,
                                                   u16* o0, u16* o1, u16* o2, u16* o3)
{
    __shared__ float red[8];
    const int t = threadIdx.x;
    if (blockIdx.x < 4096) {
        const int blk = blockIdx.x;
        const int which = blk >> 10;
        const int lb = blk & 1023;
        const float* src = which == 0 ? w0 : which == 1 ? w1 : which == 2 ? w2 : w3;
        u16* dst = which == 0 ? o0 : which == 1 ? o1 : which == 2 ? o2 : o3;
        const int idx = (lb * 256 + t) * 4;
        const float4 f = *(const float4*)(src + idx);
        union { u16 s[4]; uint2 v; } p;
        p.s[0] = f2bf(f.x); p.s[1] = f2bf(f.y); p.s[2] = f2bf(f.z); p.s[3] = f2bf(f.w);
        *(uint2*)(dst + idx) = p.v;
        return;
    }
    const int row = blockIdx.x - 4096;
    const float4 xv = ((const float4*)(x + (size_t)row * HID))[t];
    float s  = xv.x + xv.y + xv.z + xv.w;
    float ss = xv.x * xv.x + xv.y * xv.y + xv.z * xv.z + xv.w * xv.w;
#pragma unroll
    for (int off = 32; off > 0; off >>= 1) {
        s  += __shfl_down(s, off);
        ss += __shfl_down(ss, off);
    }
    const int wid = t >> 6;
    if ((t & 63) == 0) { red[wid] = s; red[4 + wid] = ss; }
    __syncthreads();
    s  = red[0] + red[1] + red[2] + red[3];
    ss = red[4] + red[5] + red[6] + red[7];
    const float mu   = s * (1.0f / HID);
    const float var  = ss * (1.0f / HID) - mu * mu;
    const float rstd = rsqrtf(var + 1e-12f);
    const float4 g  = ((const float4*)gamma)[t];
    const float4 bb = ((const float4*)beta)[t];
    union { u16 s[4]; uint2 v; } p;
    p.s[0] = f2bf((xv.x - mu) * rstd * g.x + bb.x);
    p.s[1] = f2bf((xv.y - mu) * rstd * g.y + bb.y);
    p.s[2] = f2bf((xv.z - mu) * rstd * g.z + bb.z);
    p.s[3] = f2bf((xv.w - mu) * rstd * g.w + bb.w);
    ((uint2*)(h + (size_t)row * HID))[t] = p.v;
}

// ---------------------------------------------------------------------------
// MFMA GEMM core: 128x128 tile, BK=32, 4 waves 2x2, wave = 64x64.
// A[M,K], B[N,K] row-major bf16 (C = A * B^T).  vstrB: row stride of B... here
// both A/B use K as stride (square weights), unchanged from round 3.
// ---------------------------------------------------------------------------
static __device__ __forceinline__ void gemm_core(const u16* __restrict__ A,
                                                 const u16* __restrict__ B,
                                                 int K, int bm, int bn,
                                                 u16* As, u16* Bs,
                                                 int wave, int lane,
                                                 f32x4 acc[4][4])
{
    const int l15  = lane & 15;
    const int quad = lane >> 4;
    const int wm = (wave >> 1) * 64;
    const int wn = (wave & 1) * 64;

    const int c1 = wave * 64 + lane;
    const int c2 = c1 + 256;
    const u16* A1 = A + (size_t)(bm + (c1 >> 2)) * K + (c1 & 3) * 8;
    const u16* A2 = A + (size_t)(bm + (c2 >> 2)) * K + (c2 & 3) * 8;
    const u16* B1 = B + (size_t)(bn + (c1 >> 2)) * K + (c1 & 3) * 8;
    const u16* B2 = B + (size_t)(bn + (c2 >> 2)) * K + (c2 & 3) * 8;
    u16* lA1 = As + wave * 512;
    u16* lA2 = As + 2048 + wave * 512;
    u16* lB1 = Bs + wave * 512;
    u16* lB2 = Bs + 2048 + wave * 512;

    for (int k0 = 0; k0 < K; k0 += 32) {
        __syncthreads();
        ldsload16(A1 + k0, lA1);
        ldsload16(A2 + k0, lA2);
        ldsload16(B1 + k0, lB1);
        ldsload16(B2 + k0, lB2);
        __syncthreads();
        bf16x8 af[4], bfr[4];
#pragma unroll
        for (int mt = 0; mt < 4; mt++)
            af[mt] = *(const bf16x8*)&As[(wm + mt * 16 + l15) * 32 + quad * 8];
#pragma unroll
        for (int nt = 0; nt < 4; nt++)
            bfr[nt] = *(const bf16x8*)&Bs[(wn + nt * 16 + l15) * 32 + quad * 8];
#pragma unroll
        for (int mt = 0; mt < 4; mt++)
#pragma unroll
            for (int nt = 0; nt < 4; nt++)
                acc[mt][nt] = mfma16(af[mt], bfr[nt], acc[mt][nt]);
    }
}

// ---------------------------------------------------------------------------
// Fused QKV.  Blocks 0..255: q.  256..511: k.  512..767: V' = Wv*h^T with
// padded row stride VSTR.
// ---------------------------------------------------------------------------
__global__ __launch_bounds__(256) void qkv_gemm(const u16* __restrict__ h,
                                                const u16* __restrict__ wq,
                                                const u16* __restrict__ wk,
                                                const u16* __restrict__ wv,
                                                const float* __restrict__ bq,
                                                const float* __restrict__ bk,
                                                const float* __restrict__ bv,
                                                u16* __restrict__ qo,
                                                u16* __restrict__ ko,
                                                u16* __restrict__ vo)
{
    __shared__ u16 As[4096];
    __shared__ u16 Bs[4096];
    const int blk  = blockIdx.x;
    const int wave = threadIdx.x >> 6;
    const int lane = threadIdx.x & 63;
    const int l15  = lane & 15;
    const int quad = lane >> 4;
    const int wm = (wave >> 1) * 64;
    const int wn = (wave & 1) * 64;

    f32x4 acc[4][4];
#pragma unroll
    for (int mt = 0; mt < 4; mt++)
#pragma unroll
        for (int nt = 0; nt < 4; nt++) acc[mt][nt] = (f32x4)0.0f;

    if (blk < 512) {
        const u16* W     = (blk < 256) ? wq : wk;
        const float* bia = (blk < 256) ? bq : bk;
        u16* out         = (blk < 256) ? qo : ko;
        const int local = blk & 255;
        const int bm = (local >> 3) * 128;
        const int bn = (local & 7) * 128;
        gemm_core(h, W, HID, bm, bn, As, Bs, wave, lane, acc);

        float bv4[4];
#pragma unroll
        for (int nt = 0; nt < 4; nt++) bv4[nt] = bia[bn + wn + nt * 16 + l15];
#pragma unroll
        for (int mt = 0; mt < 4; mt++)
#pragma unroll
            for (int r = 0; r < 4; r++) {
                const int m  = bm + wm + mt * 16 + quad * 4 + r;
                const int bI = m >> 11;
                const int sI = m & (SEQ - 1);
#pragma unroll
                for (int nt = 0; nt < 4; nt++) {
                    const int n  = bn + wn + nt * 16 + l15;
                    const int hh = n >> 6;
                    const int d  = n & 63;
                    out[(((size_t)(bI * NH + hh) * SEQ + sI) << 6) + d] =
                        f2bf(acc[mt][nt][r] + bv4[nt]);
                }
            }
    } else {
        const int local = blk - 512;
        const int bm = (local & 7) * 128;
        const int bn = (local >> 3) * 128;
        gemm_core(wv, h, HID, bm, bn, As, Bs, wave, lane, acc);

#pragma unroll
        for (int mt = 0; mt < 4; mt++) {
            const f32x4 bm4 = *(const f32x4*)&bv[bm + wm + mt * 16 + quad * 4];
#pragma unroll
            for (int r = 0; r < 4; r++) {
                const int row = bm + wm + mt * 16 + quad * 4 + r;
#pragma unroll
                for (int nt = 0; nt < 4; nt++) {
                    const int col = bn + wn + nt * 16 + l15;
                    vo[(size_t)row * VSTR + col] = f2bf(acc[mt][nt][r] + bm4[r]);
                }
            }
        }
    }
}

// ---------------------------------------------------------------------------
// Output projection: out = ctx * Wd^T + bd, fp32 out.
// ---------------------------------------------------------------------------
__global__ __launch_bounds__(256) void out_gemm(const u16* __restrict__ ctx,
                                                const u16* __restrict__ wd,
                                                const float* __restrict__ bd,
                                                float* __restrict__ out)
{
    __shared__ u16 As[4096];
    __shared__ u16 Bs[4096];
    const int blk  = blockIdx.x;
    const int wave = threadIdx.x >> 6;
    const int lane = threadIdx.x & 63;
    const int l15  = lane & 15;
    const int quad = lane >> 4;
    const int wm = (wave >> 1) * 64;
    const int wn = (wave & 1) * 64;
    const int bm = (blk >> 3) * 128;
    const int bn = (blk & 7) * 128;

    f32x4 acc[4][4];
#pragma unroll
    for (int mt = 0; mt < 4; mt++)
#pragma unroll
        for (int nt = 0; nt < 4; nt++) acc[mt][nt] = (f32x4)0.0f;

    gemm_core(ctx, wd, HID, bm, bn, As, Bs, wave, lane, acc);

    float bv4[4];
#pragma unroll
    for (int nt = 0; nt < 4; nt++) bv4[nt] = bd[bn + wn + nt * 16 + l15];
#pragma unroll
    for (int mt = 0; mt < 4; mt++)
#pragma unroll
        for (int r = 0; r < 4; r++) {
            const int m = bm + wm + mt * 16 + quad * 4 + r;
#pragma unroll
            for (int nt = 0; nt < 4; nt++) {
                const int n = bn + wn + nt * 16 + l15;
                out[(size_t)m * HID + n] = acc[mt][nt][r] + bv4[nt];
            }
        }
}

// ---------------------------------------------------------------------------
// MFMA flash attention v2.
//  - 1024 blocks, blk = qt*32 + bh  (same-(b,h) q-tiles -> same XCD, K/V in L2)
//  - block = 64 q rows, 4 waves, wave = 16 q x full KV scan
//  - fixed-M exp2-domain softmax (shift-invariant): no running max/rescale
//  - K/V staged via global_load_lds into XOR-swizzled [64][64] tiles
// ---------------------------------------------------------------------------
__global__ __launch_bounds__(256) void attn_mfma(const u16* __restrict__ qb,
                                                 const u16* __restrict__ kb,
                                                 const u16* __restrict__ vtb,
                                                 const float* __restrict__ maskg,
                                                 u16* __restrict__ ctx)
{
    // [0,8192) Ks [64][64] swizzled | [8192,16384) Vts | [16384,25600) P 4x[16][72]
    // [25600,25856) Ms2.  Epilogue reuses [0,17408) as 4 x float[16][68].
    __shared__ __align__(16) char smem[25856];
    u16* Ks  = (u16*)smem;
    u16* Vts = (u16*)(smem + 8192);
    u16 (*Pw)[72] = (u16(*)[72])(smem + 16384 + (threadIdx.x >> 6) * 2304);
    float* Ms2 = (float*)(smem + 25600);

    const int t    = threadIdx.x;
    const int wave = t >> 6;
    const int lane = t & 63;
    const int l15  = lane & 15;
    const int quad = lane >> 4;

    const int bh = blockIdx.x & 31;       // XCD swizzle: bh fastest
    const int qt = blockIdx.x >> 5;
    const int b  = bh >> 4;
    const int hh = bh & 15;
    const int q0 = qt * 64;

    const size_t headoff = (size_t)(b * NH + hh) * SEQ * HD;
    const u16* kbase = kb + headoff;
    const u16* vbase = vtb + (size_t)(hh * HD) * VSTR + b * SEQ;

    // Q fragment (B-operand): lane holds Q[q = l15][k = ks*32 + quad*8 + j]
    bf16x8 Qf[2];
    {
        const int qrow = q0 + wave * 16 + l15;
#pragma unroll
        for (int ks = 0; ks < 2; ks++)
            Qf[ks] = *(const bf16x8*)(qb + headoff + (size_t)qrow * HD + ks * 32 + quad * 8);
    }

    f32x4 O[4];
#pragma unroll
    for (int mt = 0; mt < 4; mt++) O[mt] = (f32x4)0.0f;
    float lsum = 0.0f;

    // staging geometry: group g = wave*2 + p covers rows [g*8, g*8+8);
    // lane -> row g*8 + (lane>>3), physical chunk lane&7, logical = phys ^ (row&7)
    const int srow = lane >> 3;
    const int lcol = (lane & 7) ^ srow;     // logical 16B chunk for this lane
    // swizzled fragment-read chunk offsets (u16 units)
    const int sw0 = ((quad)     ^ (l15 & 7)) * 8;
    const int sw1 = ((quad + 4) ^ (l15 & 7)) * 8;

    for (int c0 = 0; c0 < SEQ; c0 += 64) {
        __syncthreads();
        {
            const int g0 = wave * 2;
            ldsload16(kbase + (size_t)(c0 + g0 * 8 + srow) * HD + lcol * 8,
                      (char*)Ks + g0 * 1024);
            ldsload16(kbase + (size_t)(c0 + g0 * 8 + 8 + srow) * HD + lcol * 8,
                      (char*)Ks + g0 * 1024 + 1024);
            ldsload16(vbase + (size_t)(g0 * 8 + srow) * VSTR + c0 + lcol * 8,
                      (char*)Vts + g0 * 1024);
            ldsload16(vbase + (size_t)(g0 * 8 + 8 + srow) * VSTR + c0 + lcol * 8,
                      (char*)Vts + g0 * 1024 + 1024);
            if (t < 64)
                Ms2[t] = fmaf(-1000.0f * (1.0f - maskg[b * SEQ + c0 + t]), LOG2E, -M2F);
        }
        __syncthreads();

        // S^T: D[m=kv][n=q] = sum_d K[kv][d] * Q[q][d]
        f32x4 St[4];
#pragma unroll
        for (int mt = 0; mt < 4; mt++) {
            const int rb = (mt * 16 + l15) * 64;
            const bf16x8 ka0 = *(const bf16x8*)&Ks[rb + sw0];
            const bf16x8 ka1 = *(const bf16x8*)&Ks[rb + sw1];
            f32x4 a = (f32x4)0.0f;
            a = mfma16(ka0, Qf[0], a);
            a = mfma16(ka1, Qf[1], a);
            St[mt] = a;
        }

        // p = exp2(score*C2 + mask2 - M2); accumulate per-lane partial l
#pragma unroll
        for (int mt = 0; mt < 4; mt++) {
            const f32x4 mv = *(const f32x4*)&Ms2[mt * 16 + quad * 4];
            union { u16 s[4]; uint2 v; } pk;
#pragma unroll
            for (int r = 0; r < 4; r++) {
                const float p = __builtin_amdgcn_exp2f(fmaf(St[mt][r], C2, mv[r]));
                lsum += p;
                pk.s[r] = f2bf(p);
            }
            *(uint2*)&Pw[l15][mt * 16 + quad * 4] = pk.v;
        }

        // P fragment (B-operand): P[q = l15][kv = ks*32 + quad*8 + j]
        const bf16x8 Pb0 = *(const bf16x8*)&Pw[l15][quad * 8];
        const bf16x8 Pb1 = *(const bf16x8*)&Pw[l15][32 + quad * 8];

        // O^T: D[m=d][n=q] += sum_kv V[kv][d] * P[q][kv]
#pragma unroll
        for (int mt = 0; mt < 4; mt++) {
            const int rb = (mt * 16 + l15) * 64;
            const bf16x8 va0 = *(const bf16x8*)&Vts[rb + sw0];
            const bf16x8 va1 = *(const bf16x8*)&Vts[rb + sw1];
            O[mt] = mfma16(va0, Pb0, O[mt]);
            O[mt] = mfma16(va1, Pb1, O[mt]);
        }
    }

    // reduce l across quads (same q column lives in lanes {l15, l15+16, +32, +48})
    lsum += __shfl_xor(lsum, 16);
    lsum += __shfl_xor(lsum, 32);
    const float linv = 1.0f / lsum;

    // epilogue: O^T -> [q][d] via LDS, then coalesced bf16 store
    __syncthreads();
    float* Ot = (float*)smem + wave * (16 * 68);
#pragma unroll
    for (int mt = 0; mt < 4; mt++) {
        f32x4 v = O[mt] * linv;
        *(f32x4*)(Ot + l15 * 68 + mt * 16 + quad * 4) = v;
    }
    __syncthreads();
    {
        const int ql  = lane >> 2;
        const int seg = lane & 3;
        const float* srcp = Ot + ql * 68 + seg * 16;
        u16* dstp = ctx + (size_t)(b * SEQ + q0 + wave * 16 + ql) * HID
                        + hh * 64 + seg * 16;
#pragma unroll
        for (int j = 0; j < 2; j++) {
            union { u16 s[8]; uint4 v; } p;
#pragma unroll
            for (int i = 0; i < 8; i++) p.s[i] = f2bf(srcp[j * 8 + i]);
            *(uint4*)(dstp + j * 8) = p.v;
        }
    }
}

// ---------------------------------------------------------------------------
extern "C" void kernel_launch(void* const* d_in, const int* in_sizes, int n_in,
                              void* d_out, int out_size, void* d_ws, size_t ws_size,
                              hipStream_t stream)
{
    const float* hs    = (const float*)d_in[0];
    const float* mask  = (const float*)d_in[1];
    const float* Wq    = (const float*)d_in[2];
    const float* bq    = (const float*)d_in[3];
    const float* Wk    = (const float*)d_in[4];
    const float* bk    = (const float*)d_in[5];
    const float* Wv    = (const float*)d_in[6];
    const float* bv    = (const float*)d_in[7];
    const float* Wd    = (const float*)d_in[8];
    const float* bd    = (const float*)d_in[9];
    const float* gamma = (const float*)d_in[10];
    const float* beta  = (const float*)d_in[11];
    float* out = (float*)d_out;

    const size_t NE = (size_t)MROWS * HID;
    u16* ws   = (u16*)d_ws;
    u16* h    = ws;                          // bf16 [MROWS][HID]
    u16* qbb  = ws + NE;                     // bf16 [B,NH,S,HD]
    u16* kbb  = qbb + NE;                    // bf16 [B,NH,S,HD]
    u16* vtb  = kbb + NE;                    // bf16 [HID][VSTR]
    u16* ctxb = vtb + (size_t)HID * VSTR;    // bf16 [MROWS][HID]
    u16* wqb  = ctxb + NE;
    u16* wkb  = wqb + HID * HID;
    u16* wvb  = wkb + HID * HID;
    u16* wdb  = wvb + HID * HID;

    prep_kernel<<<8192, 256, 0, stream>>>(hs, gamma, beta, h,
                                          Wq, Wk, Wv, Wd, wqb, wkb, wvb, wdb);

    qkv_gemm<<<768, 256, 0, stream>>>(h, wqb, wkb, wvb, bq, bk, bv, qbb, kbb, vtb);

    attn_mfma<<<1024, 256, 0, stream>>>(qbb, kbb, vtb, mask, ctxb);

    out_gemm<<<256, 256, 0, stream>>>(ctxb, wdb, bd, out);
}

// Round 5
// 222.394 us; speedup vs baseline: 6.1965x; 1.0650x over previous
//
#include <hip/hip_runtime.h>
#include <hip/hip_bf16.h>
#include <math.h>

#define BATCH 2
#define SEQ   2048
#define HID   1024
#define NH    16
#define HD    64
#define MROWS (BATCH * SEQ)   // 4096
#define VSTR  4160            // padded row stride of V' (avoid 8192B channel camping)

typedef unsigned short u16;
typedef short bf16x8 __attribute__((ext_vector_type(8)));
typedef float f32x4  __attribute__((ext_vector_type(4)));

#define LOG2E 1.4426950408889634f
#define C2    (0.125f * LOG2E)      // score scale folded into log2 domain
#define M2F   23.083120f            // fixed softmax shift (shift-invariant)

static __device__ __forceinline__ u16 f2bf(float f) {
    union { float f; unsigned int u; } v; v.f = f;
    unsigned int r = (v.u + 0x7FFF + ((v.u >> 16) & 1)) >> 16;  // RNE
    return (u16)r;
}

static __device__ __forceinline__ unsigned int pk_bf16(float a, float b) {
    union { __hip_bfloat162 h; unsigned int u; } r;
    float2 f; f.x = a; f.y = b;
    r.h = __float22bfloat162_rn(f);   // packed cvt where HW supports it
    return r.u;
}

static __device__ __forceinline__ f32x4 mfma16(bf16x8 a, bf16x8 b, f32x4 c) {
    return __builtin_amdgcn_mfma_f32_16x16x32_bf16(a, b, c, 0, 0, 0);
}

// global -> LDS async copy, 16 B per lane; LDS dest = wave-uniform base + lane*16.
static __device__ __forceinline__ void ldsload16(const void* g, void* l) {
    __builtin_amdgcn_global_load_lds(
        (const __attribute__((address_space(1))) void*)(unsigned long long)(uintptr_t)g,
        (__attribute__((address_space(3))) void*)(unsigned int)(uintptr_t)l,
        16, 0, 0);
}

// ---------------------------------------------------------------------------
// Fused prep: [0,4096) weight cast; [4096,8192) LayerNorm; [8192,8196) mask2
// precompute: mask2[s] = -1000*(1-mask)*LOG2E - M2F.
// ---------------------------------------------------------------------------
__global__ __launch_bounds__(256) void prep_kernel(const float* __restrict__ x,
                                                   const float* __restrict__ gamma,
                                                   const float* __restrict__ beta,
                                                   u16* __restrict__ h,
                                                   const float* __restrict__ w0,
                                                   const float* __restrict__ w1,
                                                   const float* __restrict__ w2,
                                                   const float* __restrict__ w3,
                                                   u16* o0, u16* o1, u16* o2, u16* o3,
                                                   const float* __restrict__ maskg,
                                                   float* __restrict__ m2g)
{
    __shared__ float red[8];
    const int t = threadIdx.x;
    if (blockIdx.x >= 8192) {
        const int idx = ((blockIdx.x - 8192) * 256 + t) * 4;
        const float4 m = *(const float4*)(maskg + idx);
        float4 o;
        o.x = fmaf(-1000.0f * (1.0f - m.x), LOG2E, -M2F);
        o.y = fmaf(-1000.0f * (1.0f - m.y), LOG2E, -M2F);
        o.z = fmaf(-1000.0f * (1.0f - m.z), LOG2E, -M2F);
        o.w = fmaf(-1000.0f * (1.0f - m.w), LOG2E, -M2F);
        *(float4*)(m2g + idx) = o;
        return;
    }
    if (blockIdx.x < 4096) {
        const int blk = blockIdx.x;
        const int which = blk >> 10;
        const int lb = blk & 1023;
        const float* src = which == 0 ? w0 : which == 1 ? w1 : which == 2 ? w2 : w3;
        u16* dst = which == 0 ? o0 : which == 1 ? o1 : which == 2 ? o2 : o3;
        const int idx = (lb * 256 + t) * 4;
        const float4 f = *(const float4*)(src + idx);
        union { u16 s[4]; uint2 v; } p;
        p.s[0] = f2bf(f.x); p.s[1] = f2bf(f.y); p.s[2] = f2bf(f.z); p.s[3] = f2bf(f.w);
        *(uint2*)(dst + idx) = p.v;
        return;
    }
    const int row = blockIdx.x - 4096;
    const float4 xv = ((const float4*)(x + (size_t)row * HID))[t];
    float s  = xv.x + xv.y + xv.z + xv.w;
    float ss = xv.x * xv.x + xv.y * xv.y + xv.z * xv.z + xv.w * xv.w;
#pragma unroll
    for (int off = 32; off > 0; off >>= 1) {
        s  += __shfl_down(s, off);
        ss += __shfl_down(ss, off);
    }
    const int wid = t >> 6;
    if ((t & 63) == 0) { red[wid] = s; red[4 + wid] = ss; }
    __syncthreads();
    s  = red[0] + red[1] + red[2] + red[3];
    ss = red[4] + red[5] + red[6] + red[7];
    const float mu   = s * (1.0f / HID);
    const float var  = ss * (1.0f / HID) - mu * mu;
    const float rstd = rsqrtf(var + 1e-12f);
    const float4 g  = ((const float4*)gamma)[t];
    const float4 bb = ((const float4*)beta)[t];
    union { u16 s[4]; uint2 v; } p;
    p.s[0] = f2bf((xv.x - mu) * rstd * g.x + bb.x);
    p.s[1] = f2bf((xv.y - mu) * rstd * g.y + bb.y);
    p.s[2] = f2bf((xv.z - mu) * rstd * g.z + bb.z);
    p.s[3] = f2bf((xv.w - mu) * rstd * g.w + bb.w);
    ((uint2*)(h + (size_t)row * HID))[t] = p.v;
}

// ---------------------------------------------------------------------------
// MFMA GEMM core, double-buffered: 128x128 tile, BK=32, 4 waves 2x2, wave=64x64.
// A[M,K], B[N,K] row-major bf16 (C = A * B^T).  As/Bs are 8192-u16 (2 buffers).
// Single barrier per K-step: prefetch next tile right after the barrier, then
// compute current — loads get the whole MFMA window to complete.
// ---------------------------------------------------------------------------
static __device__ __forceinline__ void gemm_core(const u16* __restrict__ A,
                                                 const u16* __restrict__ B,
                                                 int K, int bm, int bn,
                                                 u16* As, u16* Bs,
                                                 int wave, int lane,
                                                 f32x4 acc[4][4])
{
    const int l15  = lane & 15;
    const int quad = lane >> 4;
    const int wm = (wave >> 1) * 64;
    const int wn = (wave & 1) * 64;

    const int c1 = wave * 64 + lane;
    const int c2 = c1 + 256;
    const u16* A1 = A + (size_t)(bm + (c1 >> 2)) * K + (c1 & 3) * 8;
    const u16* A2 = A + (size_t)(bm + (c2 >> 2)) * K + (c2 & 3) * 8;
    const u16* B1 = B + (size_t)(bn + (c1 >> 2)) * K + (c1 & 3) * 8;
    const u16* B2 = B + (size_t)(bn + (c2 >> 2)) * K + (c2 & 3) * 8;
    const int o1 = wave * 512;
    const int o2 = 2048 + wave * 512;

    // stage K-step 0 into buffer 0
    ldsload16(A1, As + o1);
    ldsload16(A2, As + o2);
    ldsload16(B1, Bs + o1);
    ldsload16(B2, Bs + o2);

    const int nstep = K >> 5;
    for (int i = 0; i < nstep; i++) {
        __syncthreads();                      // drains step-i loads (vmcnt 0)
        const int cb = (i & 1) * 4096;
        if (i + 1 < nstep) {
            const int nb = ((i + 1) & 1) * 4096;
            const int k0 = (i + 1) * 32;
            ldsload16(A1 + k0, As + nb + o1);
            ldsload16(A2 + k0, As + nb + o2);
            ldsload16(B1 + k0, Bs + nb + o1);
            ldsload16(B2 + k0, Bs + nb + o2);
        }
        bf16x8 af[4], bfr[4];
#pragma unroll
        for (int mt = 0; mt < 4; mt++)
            af[mt] = *(const bf16x8*)&As[cb + (wm + mt * 16 + l15) * 32 + quad * 8];
#pragma unroll
        for (int nt = 0; nt < 4; nt++)
            bfr[nt] = *(const bf16x8*)&Bs[cb + (wn + nt * 16 + l15) * 32 + quad * 8];
#pragma unroll
        for (int mt = 0; mt < 4; mt++)
#pragma unroll
            for (int nt = 0; nt < 4; nt++)
                acc[mt][nt] = mfma16(af[mt], bfr[nt], acc[mt][nt]);
    }
}

// ---------------------------------------------------------------------------
// Fused QKV.  Blocks 0..255: q.  256..511: k.  512..767: V' = Wv*h^T (VSTR).
// ---------------------------------------------------------------------------
__global__ __launch_bounds__(256) void qkv_gemm(const u16* __restrict__ h,
                                                const u16* __restrict__ wq,
                                                const u16* __restrict__ wk,
                                                const u16* __restrict__ wv,
                                                const float* __restrict__ bq,
                                                const float* __restrict__ bk,
                                                const float* __restrict__ bv,
                                                u16* __restrict__ qo,
                                                u16* __restrict__ ko,
                                                u16* __restrict__ vo)
{
    __shared__ u16 As[8192];
    __shared__ u16 Bs[8192];
    const int blk  = blockIdx.x;
    const int wave = threadIdx.x >> 6;
    const int lane = threadIdx.x & 63;
    const int l15  = lane & 15;
    const int quad = lane >> 4;
    const int wm = (wave >> 1) * 64;
    const int wn = (wave & 1) * 64;

    f32x4 acc[4][4];
#pragma unroll
    for (int mt = 0; mt < 4; mt++)
#pragma unroll
        for (int nt = 0; nt < 4; nt++) acc[mt][nt] = (f32x4)0.0f;

    if (blk < 512) {
        const u16* W     = (blk < 256) ? wq : wk;
        const float* bia = (blk < 256) ? bq : bk;
        u16* out         = (blk < 256) ? qo : ko;
        const int local = blk & 255;
        const int bm = (local >> 3) * 128;
        const int bn = (local & 7) * 128;
        gemm_core(h, W, HID, bm, bn, As, Bs, wave, lane, acc);

        float bv4[4];
#pragma unroll
        for (int nt = 0; nt < 4; nt++) bv4[nt] = bia[bn + wn + nt * 16 + l15];
#pragma unroll
        for (int mt = 0; mt < 4; mt++)
#pragma unroll
            for (int r = 0; r < 4; r++) {
                const int m  = bm + wm + mt * 16 + quad * 4 + r;
                const int bI = m >> 11;
                const int sI = m & (SEQ - 1);
#pragma unroll
                for (int nt = 0; nt < 4; nt++) {
                    const int n  = bn + wn + nt * 16 + l15;
                    const int hh = n >> 6;
                    const int d  = n & 63;
                    out[(((size_t)(bI * NH + hh) * SEQ + sI) << 6) + d] =
                        f2bf(acc[mt][nt][r] + bv4[nt]);
                }
            }
    } else {
        const int local = blk - 512;
        const int bm = (local & 7) * 128;
        const int bn = (local >> 3) * 128;
        gemm_core(wv, h, HID, bm, bn, As, Bs, wave, lane, acc);

#pragma unroll
        for (int mt = 0; mt < 4; mt++) {
            const f32x4 bm4 = *(const f32x4*)&bv[bm + wm + mt * 16 + quad * 4];
#pragma unroll
            for (int r = 0; r < 4; r++) {
                const int row = bm + wm + mt * 16 + quad * 4 + r;
#pragma unroll
                for (int nt = 0; nt < 4; nt++) {
                    const int col = bn + wn + nt * 16 + l15;
                    vo[(size_t)row * VSTR + col] = f2bf(acc[mt][nt][r] + bm4[r]);
                }
            }
        }
    }
}

// ---------------------------------------------------------------------------
// Output projection: out = ctx * Wd^T + bd, fp32 out.
// ---------------------------------------------------------------------------
__global__ __launch_bounds__(256) void out_gemm(const u16* __restrict__ ctx,
                                                const u16* __restrict__ wd,
                                                const float* __restrict__ bd,
                                                float* __restrict__ out)
{
    __shared__ u16 As[8192];
    __shared__ u16 Bs[8192];
    const int blk  = blockIdx.x;
    const int wave = threadIdx.x >> 6;
    const int lane = threadIdx.x & 63;
    const int l15  = lane & 15;
    const int quad = lane >> 4;
    const int wm = (wave >> 1) * 64;
    const int wn = (wave & 1) * 64;
    const int bm = (blk >> 3) * 128;
    const int bn = (blk & 7) * 128;

    f32x4 acc[4][4];
#pragma unroll
    for (int mt = 0; mt < 4; mt++)
#pragma unroll
        for (int nt = 0; nt < 4; nt++) acc[mt][nt] = (f32x4)0.0f;

    gemm_core(ctx, wd, HID, bm, bn, As, Bs, wave, lane, acc);

    float bv4[4];
#pragma unroll
    for (int nt = 0; nt < 4; nt++) bv4[nt] = bd[bn + wn + nt * 16 + l15];
#pragma unroll
    for (int mt = 0; mt < 4; mt++)
#pragma unroll
        for (int r = 0; r < 4; r++) {
            const int m = bm + wm + mt * 16 + quad * 4 + r;
#pragma unroll
            for (int nt = 0; nt < 4; nt++) {
                const int n = bn + wn + nt * 16 + l15;
                out[(size_t)m * HID + n] = acc[mt][nt][r] + bv4[nt];
            }
        }
}

// ---------------------------------------------------------------------------
// MFMA flash attention v3: double-buffered K/V staging, single barrier per
// KV tile (prefetch after barrier, compute immediately), per-lane f32x4 mask
// loads from precomputed mask2, packed bf16 cvt for P.
// ---------------------------------------------------------------------------
__global__ __launch_bounds__(256) void attn_mfma(const u16* __restrict__ qb,
                                                 const u16* __restrict__ kb,
                                                 const u16* __restrict__ vtb,
                                                 const float* __restrict__ m2g,
                                                 u16* __restrict__ ctx)
{
    // K bufs @0,8192 | V bufs @16384,24576 | P @32768 (4 waves x 2304 B)
    // epilogue reuses [0,17408) as 4 x float[16][68]
    __shared__ __align__(16) char smem[41984];
    u16 (*Pw)[72] = (u16(*)[72])(smem + 32768 + (threadIdx.x >> 6) * 2304);

    const int t    = threadIdx.x;
    const int wave = t >> 6;
    const int lane = t & 63;
    const int l15  = lane & 15;
    const int quad = lane >> 4;

    const int bh = blockIdx.x & 31;       // XCD swizzle: bh fastest
    const int qt = blockIdx.x >> 5;
    const int b  = bh >> 4;
    const int hh = bh & 15;
    const int q0 = qt * 64;

    const size_t headoff = (size_t)(b * NH + hh) * SEQ * HD;
    const u16* kbase = kb + headoff;
    const u16* vbase = vtb + (size_t)(hh * HD) * VSTR + b * SEQ;
    const float* m2b = m2g + b * SEQ;

    bf16x8 Qf[2];
    {
        const int qrow = q0 + wave * 16 + l15;
#pragma unroll
        for (int ks = 0; ks < 2; ks++)
            Qf[ks] = *(const bf16x8*)(qb + headoff + (size_t)qrow * HD + ks * 32 + quad * 8);
    }

    f32x4 O[4];
#pragma unroll
    for (int mt = 0; mt < 4; mt++) O[mt] = (f32x4)0.0f;
    float lsum = 0.0f;

    const int srow = lane >> 3;
    const int lcol = (lane & 7) ^ srow;       // XOR-swizzled staging chunk
    const int sw0 = ((quad)     ^ (l15 & 7)) * 8;
    const int sw1 = ((quad + 4) ^ (l15 & 7)) * 8;
    const int g0 = wave * 2;

    // stage tile 0 into buffer 0
    ldsload16(kbase + (size_t)(g0 * 8 + srow) * HD + lcol * 8,      smem + g0 * 1024);
    ldsload16(kbase + (size_t)(g0 * 8 + 8 + srow) * HD + lcol * 8,  smem + g0 * 1024 + 1024);
    ldsload16(vbase + (size_t)(g0 * 8 + srow) * VSTR + lcol * 8,    smem + 16384 + g0 * 1024);
    ldsload16(vbase + (size_t)(g0 * 8 + 8 + srow) * VSTR + lcol * 8,smem + 16384 + g0 * 1024 + 1024);

    for (int i = 0; i < 32; i++) {
        __syncthreads();   // drains tile-i loads; tile i-1 compute finished
        const int c0 = i * 64;
        const u16* Ks  = (const u16*)(smem + (i & 1) * 8192);
        const u16* Vts = (const u16*)(smem + 16384 + (i & 1) * 8192);
        if (i + 1 < 32) {
            const int cn = c0 + 64;
            char* nbK = smem + ((i + 1) & 1) * 8192;
            char* nbV = smem + 16384 + ((i + 1) & 1) * 8192;
            ldsload16(kbase + (size_t)(cn + g0 * 8 + srow) * HD + lcol * 8,      nbK + g0 * 1024);
            ldsload16(kbase + (size_t)(cn + g0 * 8 + 8 + srow) * HD + lcol * 8,  nbK + g0 * 1024 + 1024);
            ldsload16(vbase + (size_t)(g0 * 8 + srow) * VSTR + cn + lcol * 8,    nbV + g0 * 1024);
            ldsload16(vbase + (size_t)(g0 * 8 + 8 + srow) * VSTR + cn + lcol * 8,nbV + g0 * 1024 + 1024);
        }

        // S^T: D[m=kv][n=q] = sum_d K[kv][d] * Q[q][d]
        f32x4 St[4];
#pragma unroll
        for (int mt = 0; mt < 4; mt++) {
            const int rb = (mt * 16 + l15) * 64;
            const bf16x8 ka0 = *(const bf16x8*)&Ks[rb + sw0];
            const bf16x8 ka1 = *(const bf16x8*)&Ks[rb + sw1];
            f32x4 a = (f32x4)0.0f;
            a = mfma16(ka0, Qf[0], a);
            a = mfma16(ka1, Qf[1], a);
            St[mt] = a;
        }

        // p = exp2(score*C2 + mask2); partial l; packed bf16 P
#pragma unroll
        for (int mt = 0; mt < 4; mt++) {
            const f32x4 mv = *(const f32x4*)(m2b + c0 + mt * 16 + quad * 4);
            float p0 = __builtin_amdgcn_exp2f(fmaf(St[mt][0], C2, mv[0]));
            float p1 = __builtin_amdgcn_exp2f(fmaf(St[mt][1], C2, mv[1]));
            float p2 = __builtin_amdgcn_exp2f(fmaf(St[mt][2], C2, mv[2]));
            float p3 = __builtin_amdgcn_exp2f(fmaf(St[mt][3], C2, mv[3]));
            lsum += p0 + p1 + p2 + p3;
            uint2 w;
            w.x = pk_bf16(p0, p1);
            w.y = pk_bf16(p2, p3);
            *(uint2*)&Pw[l15][mt * 16 + quad * 4] = w;
        }

        const bf16x8 Pb0 = *(const bf16x8*)&Pw[l15][quad * 8];
        const bf16x8 Pb1 = *(const bf16x8*)&Pw[l15][32 + quad * 8];

        // O^T: D[m=d][n=q] += sum_kv V[kv][d] * P[q][kv]
#pragma unroll
        for (int mt = 0; mt < 4; mt++) {
            const int rb = (mt * 16 + l15) * 64;
            const bf16x8 va0 = *(const bf16x8*)&Vts[rb + sw0];
            const bf16x8 va1 = *(const bf16x8*)&Vts[rb + sw1];
            O[mt] = mfma16(va0, Pb0, O[mt]);
            O[mt] = mfma16(va1, Pb1, O[mt]);
        }
    }

    lsum += __shfl_xor(lsum, 16);
    lsum += __shfl_xor(lsum, 32);
    const float linv = 1.0f / lsum;

    __syncthreads();
    float* Ot = (float*)smem + wave * (16 * 68);
#pragma unroll
    for (int mt = 0; mt < 4; mt++) {
        f32x4 v = O[mt] * linv;
        *(f32x4*)(Ot + l15 * 68 + mt * 16 + quad * 4) = v;
    }
    __syncthreads();
    {
        const int ql  = lane >> 2;
        const int seg = lane & 3;
        const float* srcp = Ot + ql * 68 + seg * 16;
        u16* dstp = ctx + (size_t)(b * SEQ + q0 + wave * 16 + ql) * HID
                        + hh * 64 + seg * 16;
#pragma unroll
        for (int j = 0; j < 2; j++) {
            union { u16 s[8]; uint4 v; } p;
#pragma unroll
            for (int i = 0; i < 8; i++) p.s[i] = f2bf(srcp[j * 8 + i]);
            *(uint4*)(dstp + j * 8) = p.v;
        }
    }
}

// ---------------------------------------------------------------------------
extern "C" void kernel_launch(void* const* d_in, const int* in_sizes, int n_in,
                              void* d_out, int out_size, void* d_ws, size_t ws_size,
                              hipStream_t stream)
{
    const float* hs    = (const float*)d_in[0];
    const float* mask  = (const float*)d_in[1];
    const float* Wq    = (const float*)d_in[2];
    const float* bq    = (const float*)d_in[3];
    const float* Wk    = (const float*)d_in[4];
    const float* bk    = (const float*)d_in[5];
    const float* Wv    = (const float*)d_in[6];
    const float* bv    = (const float*)d_in[7];
    const float* Wd    = (const float*)d_in[8];
    const float* bd    = (const float*)d_in[9];
    const float* gamma = (const float*)d_in[10];
    const float* beta  = (const float*)d_in[11];
    float* out = (float*)d_out;

    const size_t NE = (size_t)MROWS * HID;
    u16* ws   = (u16*)d_ws;
    u16* h    = ws;                          // bf16 [MROWS][HID]
    u16* qbb  = ws + NE;                     // bf16 [B,NH,S,HD]
    u16* kbb  = qbb + NE;                    // bf16 [B,NH,S,HD]
    u16* vtb  = kbb + NE;                    // bf16 [HID][VSTR]
    u16* ctxb = vtb + (size_t)HID * VSTR;    // bf16 [MROWS][HID]
    u16* wqb  = ctxb + NE;
    u16* wkb  = wqb + HID * HID;
    u16* wvb  = wkb + HID * HID;
    u16* wdb  = wvb + HID * HID;
    float* m2 = (float*)(wdb + HID * HID);   // fp32 [MROWS] precomputed mask2

    prep_kernel<<<8196, 256, 0, stream>>>(hs, gamma, beta, h,
                                          Wq, Wk, Wv, Wd, wqb, wkb, wvb, wdb,
                                          mask, m2);

    qkv_gemm<<<768, 256, 0, stream>>>(h, wqb, wkb, wvb, bq, bk, bv, qbb, kbb, vtb);

    attn_mfma<<<1024, 256, 0, stream>>>(qbb, kbb, vtb, m2, ctxb);

    out_gemm<<<256, 256, 0, stream>>>(ctxb, wdb, bd, out);
}